// Round 3
// baseline (762.147 us; speedup 1.0000x reference)
//
#include <hip/hip_runtime.h>
#include <math.h>

typedef unsigned int u32;
typedef unsigned short u16;
typedef __attribute__((ext_vector_type(8))) short short8;
typedef __attribute__((ext_vector_type(4))) float float4v;

#define NBATCH 4
#define HW 65536

// ws layout (floats)
#define OFF_COV 0        // cov[8][B][64][64]   131072 floats  [0,131072)
#define OFF_T   131072   // T[10][B][64][64]    163840 floats  [131072,294912)
#define OFF_M   294912   // M[3][B][64][64]      49152 floats  [294912,344064)
#define OFF_P   344064   // P[3][B][64][64]      49152 floats  [344064,393216)
#define OFF_WC  393216   // canonical bf16 weights: 30 slots x 8192 u16 = 122880 floats

__device__ inline float bf2f(u16 h){ return __uint_as_float(((u32)h) << 16); }
__device__ inline u16 f2bf(float x){
  u32 u = __float_as_uint(x);
  u += 0x7fffu + ((u >> 16) & 1u);
  return (u16)(u >> 16);
}
__device__ inline u32 packbf2(float a, float b){
  return (u32)f2bf(a) | ((u32)f2bf(b) << 16);
}
__device__ inline float bfu(u32 u, int hi){
  return __uint_as_float(hi ? (u & 0xffff0000u) : (u << 16));
}

// Device-side dtype sniff: bf16 data has sane low-half bf16 exponents; fp32
// data's low 16 bits are mantissa noise. 256 threads vote.
__device__ inline bool detect_f32(const void* probe, int t, int* s_cnt){
  if (t == 0) *s_cnt = 0;
  __syncthreads();
  u32 w = ((const u32*)probe)[t & 255];
  u32 ex = (w >> 7) & 0xffu;
  if (!(ex >= 113u && ex <= 133u)) atomicAdd(s_cnt, 1);
  __syncthreads();
  return *s_cnt >= 128;
}

// Load 8 consecutive elements as float, from either bf16 or fp32 storage.
__device__ inline void ld8(const u16* pb, const float* pf, size_t idx, bool f32, float* o){
  if (f32){
    const float4 a = *(const float4*)(pf + idx);
    const float4 b = *(const float4*)(pf + idx + 4);
    o[0]=a.x; o[1]=a.y; o[2]=a.z; o[3]=a.w; o[4]=b.x; o[5]=b.y; o[6]=b.z; o[7]=b.w;
  } else {
    uint4 r = *(const uint4*)(pb + idx);
    const u32* p = (const u32*)&r;
    #pragma unroll
    for (int j=0;j<8;j++) o[j] = bfu(p[j>>1], j&1);
  }
}

__device__ inline void softmax16(float* l){
  float m = l[0];
  #pragma unroll
  for (int i=1;i<16;i++) m = fmaxf(m, l[i]);
  float s = 0.f;
  #pragma unroll
  for (int i=0;i<16;i++){ l[i] = __expf(l[i]-m); s += l[i]; }
  float r = 1.0f/s;
  #pragma unroll
  for (int i=0;i<16;i++) l[i] *= r;
}

// ---------------------------------------------------------------------------
// convert_all: canonicalize the 30 weight tensors to bf16 slots (8192 u16 each)
// ---------------------------------------------------------------------------
__global__ __launch_bounds__(256) void convert_all(
    const void* img,
    const void* t0, const void* t1, const void* t2, const void* t3,
    const void* t4, const void* t5, const void* t6, const void* t7,
    const void* t8, const void* t9, const void* t10, const void* t11,
    const void* t12, const void* t13, const void* t14, const void* t15,
    const void* t16, const void* t17, const void* t18, const void* t19,
    const void* t20, const void* t21, const void* t22, const void* t23,
    const void* t24, const void* t25, const void* t26, const void* t27,
    const void* t28, const void* t29,
    u16* __restrict__ wc)
{
  __shared__ int s_cnt;
  const int t = threadIdx.x;
  const bool f32 = detect_f32(img, t, &s_cnt);
  const int sizes[30] = {4096,4096,4096,4,4096,4096,4096,4,
                         64,64,64,64,64,64,64,64,64,64,64,64,
                         8192,128,8192,64,8192,128,8192,64,4096,4096};
  const void* srcs[30] = {t0,t1,t2,t3,t4,t5,t6,t7,t8,t9,t10,t11,t12,t13,t14,
                          t15,t16,t17,t18,t19,t20,t21,t22,t23,t24,t25,t26,t27,t28,t29};
  const int id = blockIdx.x;
  const void* s = srcs[id];
  const int n = sizes[id];
  u16* d = wc + (size_t)id*8192;
  for (int j = t; j < n; j += 256)
    d[j] = f32 ? f2bf(((const float*)s)[j]) : ((const u16*)s)[j];
}

// ---------------------------------------------------------------------------
// K1: per-pixel LN of {img, evt, img+evt, img-evt} -> 8 covariance matrices
// cov order: 0 cc, 1 ci, 2 ce, 3 ii, 4 dd, 5 di, 6 de, 7 ee (vec: 0=i,1=e,2=c,3=d)
// ---------------------------------------------------------------------------
__global__ __launch_bounds__(256) void k1_cov(
    const void* __restrict__ img, const void* __restrict__ evt,
    const u16* __restrict__ lniw, const u16* __restrict__ lnib,
    const u16* __restrict__ lnew, const u16* __restrict__ lneb,
    const u16* __restrict__ lncw, const u16* __restrict__ lncb,
    const u16* __restrict__ lndw, const u16* __restrict__ lndb,
    float* __restrict__ cov)
{
  __shared__ u16 NtL[4*64*72];
  __shared__ float spart[4][64][5];
  __shared__ float params[64][8];
  __shared__ int s_cnt;

  const int t = threadIdx.x;
  const bool f32 = detect_f32(img, t, &s_cnt);
  const u16* imgb = (const u16*)img; const float* imgf = (const float*)img;
  const u16* evtb = (const u16*)evt; const float* evtf = (const float*)evt;

  const int b = blockIdx.x >> 6;
  const int P0 = (blockIdx.x & 63) * 1024;
  const int chg = t >> 3, pg = t & 7, ch0 = chg*2;
  const int wave = t >> 6, lane = t & 63, l15 = lane & 15, quad = lane >> 4;

  float wi0=bf2f(lniw[ch0]), wi1=bf2f(lniw[ch0+1]);
  float bi0=bf2f(lnib[ch0]), bi1=bf2f(lnib[ch0+1]);
  float we0=bf2f(lnew[ch0]), we1=bf2f(lnew[ch0+1]);
  float be0=bf2f(lneb[ch0]), be1=bf2f(lneb[ch0+1]);
  float wc0=bf2f(lncw[ch0]), wc1=bf2f(lncw[ch0+1]);
  float bc0=bf2f(lncb[ch0]), bc1=bf2f(lncb[ch0+1]);
  float wd0=bf2f(lndw[ch0]), wd1=bf2f(lndw[ch0+1]);
  float bd0=bf2f(lndb[ch0]), bd1=bf2f(lndb[ch0+1]);

  int va1, vb1, va2, vb2;
  if (wave == 0){ va1=2; vb1=2; va2=2; vb2=0; }       // cc, ci
  else if (wave == 1){ va1=2; vb1=1; va2=0; vb2=0; }  // ce, ii
  else if (wave == 2){ va1=3; vb1=3; va2=3; vb2=0; }  // dd, di
  else { va1=3; vb1=1; va2=1; vb2=1; }                // de, ee

  float4v acc0[4][4], acc1v[4][4];
  #pragma unroll
  for (int i=0;i<4;i++)
    #pragma unroll
    for (int j=0;j<4;j++){ acc0[i][j]=(float4v)0.f; acc1v[i][j]=(float4v)0.f; }

  const size_t base_i = (size_t)(b*64 + ch0) * HW;

  for (int it = 0; it < 16; ++it){
    const int p0 = P0 + it*64;
    float A0[8], A1[8], B0[8], B1[8];   // [px j] for ch0 / ch0+1 of img / evt
    ld8(imgb, imgf, base_i + p0 + pg*8, f32, A0);
    ld8(imgb, imgf, base_i + HW + p0 + pg*8, f32, A1);
    ld8(evtb, evtf, base_i + p0 + pg*8, f32, B0);
    ld8(evtb, evtf, base_i + HW + p0 + pg*8, f32, B1);

    float si[8], sii[8], se[8], see[8], sie[8];
    #pragma unroll
    for (int j=0;j<8;j++){
      float xi0=A0[j], xi1=A1[j], xe0=B0[j], xe1=B1[j];
      si[j]  = xi0 + xi1;
      sii[j] = fmaf(xi0, xi0, xi1*xi1);
      se[j]  = xe0 + xe1;
      see[j] = fmaf(xe0, xe0, xe1*xe1);
      sie[j] = fmaf(xi0, xe0, xi1*xe1);
    }
    #pragma unroll
    for (int m=8; m<=32; m<<=1){
      #pragma unroll
      for (int j=0;j<8;j++){
        si[j]  += __shfl_xor(si[j],  m);
        sii[j] += __shfl_xor(sii[j], m);
        se[j]  += __shfl_xor(se[j],  m);
        see[j] += __shfl_xor(see[j], m);
        sie[j] += __shfl_xor(sie[j], m);
      }
    }
    if ((chg & 7) == 0){
      #pragma unroll
      for (int j=0;j<8;j++){
        spart[wave][pg*8+j][0]=si[j];  spart[wave][pg*8+j][1]=sii[j];
        spart[wave][pg*8+j][2]=se[j];  spart[wave][pg*8+j][3]=see[j];
        spart[wave][pg*8+j][4]=sie[j];
      }
    }
    __syncthreads();
    if (t < 64){
      float S0=0,S1=0,S2=0,S3=0,S4=0;
      #pragma unroll
      for (int w=0;w<4;w++){
        S0+=spart[w][t][0]; S1+=spart[w][t][1]; S2+=spart[w][t][2];
        S3+=spart[w][t][3]; S4+=spart[w][t][4];
      }
      const float inv = 0.015625f;
      float mu_i=S0*inv, mu_e=S2*inv;
      float r_i = rsqrtf(fmaf(S1,inv,-mu_i*mu_i)+1e-5f);
      float r_e = rsqrtf(fmaf(S3,inv,-mu_e*mu_e)+1e-5f);
      float mu_c=mu_i+mu_e, mu_d=mu_i-mu_e;
      float r_c = rsqrtf((S1+2.f*S4+S3)*inv - mu_c*mu_c + 1e-5f);
      float r_d = rsqrtf((S1-2.f*S4+S3)*inv - mu_d*mu_d + 1e-5f);
      params[t][0]=mu_i; params[t][1]=r_i; params[t][2]=mu_e; params[t][3]=r_e;
      params[t][4]=mu_c; params[t][5]=r_c; params[t][6]=mu_d; params[t][7]=r_d;
    }
    __syncthreads();
    // phase B: normalized vectors -> NtL[vec][ch][px]
    u32 un[4][2][4];
    #pragma unroll
    for (int jj=0;jj<4;jj++){
      float4 pA0 = *(const float4*)&params[pg*8+jj*2][0];
      float4 pB0 = *(const float4*)&params[pg*8+jj*2][4];
      float4 pA1 = *(const float4*)&params[pg*8+jj*2+1][0];
      float4 pB1 = *(const float4*)&params[pg*8+jj*2+1][4];
      float xiA0=A0[2*jj], xiA1=A1[2*jj], xeA0=B0[2*jj], xeA1=B1[2*jj];
      float xiB0=A0[2*jj+1], xiB1=A1[2*jj+1], xeB0=B0[2*jj+1], xeB1=B1[2*jj+1];
      un[0][0][jj] = packbf2(fmaf((xiA0-pA0.x)*pA0.y, wi0, bi0), fmaf((xiB0-pA1.x)*pA1.y, wi0, bi0));
      un[0][1][jj] = packbf2(fmaf((xiA1-pA0.x)*pA0.y, wi1, bi1), fmaf((xiB1-pA1.x)*pA1.y, wi1, bi1));
      un[1][0][jj] = packbf2(fmaf((xeA0-pA0.z)*pA0.w, we0, be0), fmaf((xeB0-pA1.z)*pA1.w, we0, be0));
      un[1][1][jj] = packbf2(fmaf((xeA1-pA0.z)*pA0.w, we1, be1), fmaf((xeB1-pA1.z)*pA1.w, we1, be1));
      float xcA0=xiA0+xeA0, xcA1=xiA1+xeA1, xcB0=xiB0+xeB0, xcB1=xiB1+xeB1;
      un[2][0][jj] = packbf2(fmaf((xcA0-pB0.x)*pB0.y, wc0, bc0), fmaf((xcB0-pB1.x)*pB1.y, wc0, bc0));
      un[2][1][jj] = packbf2(fmaf((xcA1-pB0.x)*pB0.y, wc1, bc1), fmaf((xcB1-pB1.x)*pB1.y, wc1, bc1));
      float xdA0=xiA0-xeA0, xdA1=xiA1-xeA1, xdB0=xiB0-xeB0, xdB1=xiB1-xeB1;
      un[3][0][jj] = packbf2(fmaf((xdA0-pB0.z)*pB0.w, wd0, bd0), fmaf((xdB0-pB1.z)*pB1.w, wd0, bd0));
      un[3][1][jj] = packbf2(fmaf((xdA1-pB0.z)*pB0.w, wd1, bd1), fmaf((xdB1-pB1.z)*pB1.w, wd1, bd1));
    }
    #pragma unroll
    for (int v=0; v<4; v++){
      *(uint4*)&NtL[(v*64 + ch0  )*72 + pg*8] = make_uint4(un[v][0][0],un[v][0][1],un[v][0][2],un[v][0][3]);
      *(uint4*)&NtL[(v*64 + ch0+1)*72 + pg*8] = make_uint4(un[v][1][0],un[v][1][1],un[v][1][2],un[v][1][3]);
    }
    __syncthreads();
    // phase C: covariance MFMAs (K = 64 px)
    #pragma unroll
    for (int ks=0; ks<2; ks++){
      const int off = ks*32 + quad*8;
      short8 A1f[4], B1f[4], A2f[4], B2f[4];
      #pragma unroll
      for (int mi=0;mi<4;mi++){
        A1f[mi] = *(const short8*)&NtL[(va1*64 + mi*16 + l15)*72 + off];
        B1f[mi] = *(const short8*)&NtL[(vb1*64 + mi*16 + l15)*72 + off];
        A2f[mi] = *(const short8*)&NtL[(va2*64 + mi*16 + l15)*72 + off];
        B2f[mi] = *(const short8*)&NtL[(vb2*64 + mi*16 + l15)*72 + off];
      }
      #pragma unroll
      for (int mi=0;mi<4;mi++)
        #pragma unroll
        for (int nj=0;nj<4;nj++){
          acc0[mi][nj]  = __builtin_amdgcn_mfma_f32_16x16x32_bf16(A1f[mi], B1f[nj], acc0[mi][nj], 0,0,0);
          acc1v[mi][nj] = __builtin_amdgcn_mfma_f32_16x16x32_bf16(A2f[mi], B2f[nj], acc1v[mi][nj], 0,0,0);
        }
    }
    __syncthreads();
  }
  float* c0 = cov + ((size_t)(wave*2 + 0)*NBATCH + b)*4096;
  float* c1 = cov + ((size_t)(wave*2 + 1)*NBATCH + b)*4096;
  #pragma unroll
  for (int mi=0;mi<4;mi++)
    #pragma unroll
    for (int nj=0;nj<4;nj++){
      int row0 = mi*16 + quad*4, col = nj*16 + l15;
      #pragma unroll
      for (int r=0;r<4;r++){
        atomicAdd(&c0[(row0+r)*64 + col], acc0[mi][nj][r]);
        atomicAdd(&c1[(row0+r)*64 + col], acc1v[mi][nj][r]);
      }
    }
}

// ---------------------------------------------------------------------------
// P2a: T = W @ C  (10 products per batch)
// ---------------------------------------------------------------------------
__global__ __launch_bounds__(256) void p2a(
    const u16* __restrict__ Wq_c, const u16* __restrict__ Wk_c,
    const u16* __restrict__ Wq_d, const u16* __restrict__ Wk_d,
    float* __restrict__ ws)
{
  __shared__ float WL[64][65];
  __shared__ float CL[64][64];
  const int t = threadIdx.x;
  const int b = blockIdx.x & 3;
  const int which = blockIdx.x >> 2;
  int wsel, csel;
  switch (which){
    case 0: wsel=0; csel=0; break;  // qc : Wq_c @ cc
    case 1: wsel=1; csel=3; break;  // kic: Wk_c @ ii
    case 2: wsel=1; csel=7; break;  // kec: Wk_c @ ee
    case 3: wsel=2; csel=4; break;  // qd : Wq_d @ dd
    case 4: wsel=3; csel=3; break;  // kid: Wk_d @ ii
    case 5: wsel=3; csel=7; break;  // ked: Wk_d @ ee
    case 6: wsel=0; csel=1; break;  // Wq_c @ ci
    case 7: wsel=0; csel=2; break;  // Wq_c @ ce
    case 8: wsel=2; csel=5; break;  // Wq_d @ di
    default: wsel=2; csel=6; break; // Wq_d @ de
  }
  const u16* W = (wsel==0)? Wq_c : (wsel==1)? Wk_c : (wsel==2)? Wq_d : Wk_d;
  const float* Cm = ws + ((size_t)csel*NBATCH + b)*4096;
  { int r = t>>2, c0 = (t&3)*16;
    #pragma unroll
    for (int i=0;i<16;i++) WL[r][c0+i] = bf2f(W[r*64 + c0 + i]);
    const float4* s = (const float4*)(Cm + r*64 + c0);
    float4* d = (float4*)&CL[r][c0];
    d[0]=s[0]; d[1]=s[1]; d[2]=s[2]; d[3]=s[3]; }
  __syncthreads();
  const int r = t>>2, k0 = (t&3)*16;
  float a[16];
  #pragma unroll
  for (int i=0;i<16;i++) a[i]=0.f;
  for (int m=0;m<64;m++){
    float wv = WL[r][m];
    #pragma unroll
    for (int i=0;i<16;i++) a[i] = fmaf(wv, CL[m][k0+i], a[i]);
  }
  float* o = ws + OFF_T + ((size_t)which*NBATCH + b)*4096 + r*64 + k0;
  #pragma unroll
  for (int i=0;i<16;i++) o[i] = a[i];
}

// ---------------------------------------------------------------------------
// P2b: norms, Gram blocks, softmax, A, M = blockdiag(A)@Wv
// ---------------------------------------------------------------------------
__global__ __launch_bounds__(256) void p2b(
    float* __restrict__ ws,
    const u16* __restrict__ Wq_c, const u16* __restrict__ Wk_c,
    const u16* __restrict__ Wq_d, const u16* __restrict__ Wk_d,
    const u16* __restrict__ Wv_c, const u16* __restrict__ Wv_d,
    const u16* __restrict__ temp_c, const u16* __restrict__ temp_d)
{
  const int b = blockIdx.x, t = threadIdx.x;
  __shared__ float rn[6][64];
  __shared__ float GLs[4][64][16];
  __shared__ float AL[3][64][16];
  const float* T = ws + OFF_T;
  {
    int s = t>>6, c = t&63;
    const float* Tp = T + ((size_t)s*NBATCH + b)*4096 + c*64;
    const u16* Wp = (s==0)? Wq_c : (s==3)? Wq_d : Wk_c;
    float acc=0;
    for (int k=0;k<64;k++) acc = fmaf(Tp[k], bf2f(Wp[c*64+k]), acc);
    rn[s][c] = 1.0f/fmaxf(sqrtf(fmaxf(acc,0.f)), 1e-12f);
    if (t < 128){
      int s2 = 4 + (t>>6);
      const float* Tp2 = T + ((size_t)s2*NBATCH + b)*4096 + c*64;
      float acc2=0;
      for (int k=0;k<64;k++) acc2 = fmaf(Tp2[k], bf2f(Wk_d[c*64+k]), acc2);
      rn[s2][c] = 1.0f/fmaxf(sqrtf(fmaxf(acc2,0.f)), 1e-12f);
    }
  }
  #pragma unroll 1
  for (int i=0;i<16;i++){
    int e = t*16 + i;
    int s = e >> 10, c = (e>>4)&63, dl = e&15, d = (c&~15)+dl;
    const float* Tp = T + ((size_t)(6+s)*NBATCH + b)*4096 + c*64;
    const u16* Wp = ((s<2)? Wk_c : Wk_d) + d*64;
    float acc=0;
    for (int j=0;j<64;j++) acc = fmaf(Tp[j], bf2f(Wp[j]), acc);
    GLs[s][c][dl] = acc;
  }
  __syncthreads();
  if (t < 192){
    int set = t>>6, c = t&63, h = c>>4, cb = c&~15;
    if (set == 0){
      float tc = bf2f(temp_c[h]);
      float rq = rn[0][c];
      float l1[16], l2[16];
      #pragma unroll
      for (int dl=0;dl<16;dl++){
        l1[dl] = GLs[0][c][dl]*rq*rn[1][cb+dl]*tc;
        l2[dl] = GLs[1][c][dl]*rq*rn[2][cb+dl]*tc;
      }
      softmax16(l1); softmax16(l2);
      #pragma unroll
      for (int dl=0;dl<16;dl++) AL[0][c][dl] = l1[dl]*l2[dl];
    } else {
      float td = bf2f(temp_d[h]);
      float rq = rn[3][c];
      int gi = (set==1)? 2 : 3;
      int rk = (set==1)? 4 : 5;
      float l[16];
      #pragma unroll
      for (int dl=0;dl<16;dl++) l[dl] = GLs[gi][c][dl]*rq*rn[rk][cb+dl]*td;
      softmax16(l);
      #pragma unroll
      for (int dl=0;dl<16;dl++) AL[set][c][dl] = l[dl];
    }
  }
  __syncthreads();
  for (int wsel=0; wsel<3; wsel++){
    const u16* Wv = (wsel==0)? Wv_c : Wv_d;
    #pragma unroll 1
    for (int i=0;i<16;i++){
      int e = t*16+i, c = e>>6, k = e&63, cb = c&~15;
      float acc=0;
      #pragma unroll
      for (int dl=0;dl<16;dl++) acc = fmaf(AL[wsel][c][dl], bf2f(Wv[(cb+dl)*64 + k]), acc);
      ws[OFF_M + ((size_t)wsel*NBATCH + b)*4096 + c*64 + k] = acc;
    }
  }
}

// ---------------------------------------------------------------------------
// P2c: P = proj @ M  (3 per batch)
// ---------------------------------------------------------------------------
__global__ __launch_bounds__(256) void p2c(
    const u16* __restrict__ proj1, const u16* __restrict__ proj2,
    float* __restrict__ ws)
{
  __shared__ float WL[64][65];
  __shared__ float CL[64][64];
  const int t = threadIdx.x;
  const int b = blockIdx.x & 3;
  const int which = blockIdx.x >> 2;  // 0: proj1@M_c, 1: proj2@M_id, 2: proj2@M_ed
  const u16* W = (which==0)? proj1 : proj2;
  const float* Cm = ws + OFF_M + ((size_t)which*NBATCH + b)*4096;
  { int r = t>>2, c0 = (t&3)*16;
    #pragma unroll
    for (int i=0;i<16;i++) WL[r][c0+i] = bf2f(W[r*64 + c0 + i]);
    const float4* s = (const float4*)(Cm + r*64 + c0);
    float4* d = (float4*)&CL[r][c0];
    d[0]=s[0]; d[1]=s[1]; d[2]=s[2]; d[3]=s[3]; }
  __syncthreads();
  const int r = t>>2, k0 = (t&3)*16;
  float a[16];
  #pragma unroll
  for (int i=0;i<16;i++) a[i]=0.f;
  for (int m=0;m<64;m++){
    float wv = WL[r][m];
    #pragma unroll
    for (int i=0;i<16;i++) a[i] = fmaf(wv, CL[m][k0+i], a[i]);
  }
  float* o = ws + OFF_P + ((size_t)which*NBATCH + b)*4096 + r*64 + k0;
  #pragma unroll
  for (int i=0;i<16;i++) o[i] = a[i];
}

// ---------------------------------------------------------------------------
// K3 common branch: out = oc + FFN(LN(oc)), oc = P_c @ (n_i + n_e)
// ---------------------------------------------------------------------------
__global__ __launch_bounds__(256) void k3_common(
    const void* __restrict__ img, const void* __restrict__ evt,
    const u16* __restrict__ lniw, const u16* __restrict__ lnib,
    const u16* __restrict__ lnew, const u16* __restrict__ lneb,
    const u16* __restrict__ ln1w, const u16* __restrict__ ln1b,
    const u16* __restrict__ fc1w, const u16* __restrict__ fc1b,
    const u16* __restrict__ fc2w, const u16* __restrict__ fc2b,
    const float* __restrict__ Pmat, void* __restrict__ outp, size_t obase)
{
  __shared__ u16 fc1L[128*72];
  __shared__ u16 fc2L[64*136];
  __shared__ u16 PcL[64*72];
  __shared__ u16 SB[64*136];
  __shared__ float spart[4][64][4];
  __shared__ float params[64][4];
  __shared__ float b1L[128];
  __shared__ float b2L[64];
  __shared__ int s_cnt;

  const int t = threadIdx.x;
  const bool f32 = detect_f32(img, t, &s_cnt);
  const u16* imgb = (const u16*)img; const float* imgf = (const float*)img;
  const u16* evtb = (const u16*)evt; const float* evtf = (const float*)evt;

  const int b = blockIdx.x >> 6;
  const int P0 = (blockIdx.x & 63) * 1024;
  const int chg = t >> 3, pg = t & 7, ch0 = chg*2;
  const int wave = t >> 6, lane = t & 63, l15 = lane & 15, quad = lane >> 4;

  { int row = t >> 1, c0 = (t & 1)*32;
    const uint4* s = (const uint4*)(fc1w + row*64 + c0);
    uint4* d = (uint4*)&fc1L[row*72 + c0];
    d[0]=s[0]; d[1]=s[1]; d[2]=s[2]; d[3]=s[3]; }
  { int row = t >> 2, c0 = (t & 3)*32;
    const uint4* s = (const uint4*)(fc2w + row*128 + c0);
    uint4* d = (uint4*)&fc2L[row*136 + c0];
    d[0]=s[0]; d[1]=s[1]; d[2]=s[2]; d[3]=s[3]; }
  { int row = t >> 2, c0 = (t & 3)*16;
    const float* s = Pmat + (size_t)b*4096 + row*64 + c0;
    u32 u[8];
    #pragma unroll
    for (int i=0;i<8;i++) u[i] = packbf2(s[2*i], s[2*i+1]);
    uint4* d = (uint4*)&PcL[row*72 + c0];
    d[0] = make_uint4(u[0],u[1],u[2],u[3]);
    d[1] = make_uint4(u[4],u[5],u[6],u[7]); }
  if (t < 128) b1L[t] = bf2f(fc1b[t]);
  if (t < 64)  b2L[t] = bf2f(fc2b[t]);

  float wi0=bf2f(lniw[ch0]), wi1=bf2f(lniw[ch0+1]);
  float we0=bf2f(lnew[ch0]), we1=bf2f(lnew[ch0+1]);
  float bs0=bf2f(lnib[ch0]) + bf2f(lneb[ch0]);
  float bs1=bf2f(lnib[ch0+1]) + bf2f(lneb[ch0+1]);
  float w1r[4], b1r[4];
  #pragma unroll
  for (int nj=0;nj<4;nj++){ w1r[nj]=bf2f(ln1w[nj*16+l15]); b1r[nj]=bf2f(ln1b[nj*16+l15]); }
  __syncthreads();

  const size_t base_i = (size_t)(b*64 + ch0)*HW;
  for (int it=0; it<16; ++it){
    const int p0 = P0 + it*64;
    float A0[8], A1[8], B0[8], B1[8];
    ld8(imgb, imgf, base_i + p0 + pg*8, f32, A0);
    ld8(imgb, imgf, base_i + HW + p0 + pg*8, f32, A1);
    ld8(evtb, evtf, base_i + p0 + pg*8, f32, B0);
    ld8(evtb, evtf, base_i + HW + p0 + pg*8, f32, B1);
    float si[8], sii[8], se[8], see[8];
    #pragma unroll
    for (int j=0;j<8;j++){
      float xi0=A0[j], xi1=A1[j], xe0=B0[j], xe1=B1[j];
      si[j]=xi0+xi1; sii[j]=fmaf(xi0,xi0,xi1*xi1);
      se[j]=xe0+xe1; see[j]=fmaf(xe0,xe0,xe1*xe1);
    }
    #pragma unroll
    for (int m=8;m<=32;m<<=1)
      #pragma unroll
      for (int j=0;j<8;j++){
        si[j]+=__shfl_xor(si[j],m); sii[j]+=__shfl_xor(sii[j],m);
        se[j]+=__shfl_xor(se[j],m); see[j]+=__shfl_xor(see[j],m);
      }
    if ((chg&7)==0){
      #pragma unroll
      for (int j=0;j<8;j++){
        spart[wave][pg*8+j][0]=si[j]; spart[wave][pg*8+j][1]=sii[j];
        spart[wave][pg*8+j][2]=se[j]; spart[wave][pg*8+j][3]=see[j];
      }
    }
    __syncthreads();
    if (t<64){
      float S0=0,S1=0,S2=0,S3=0;
      #pragma unroll
      for (int w=0;w<4;w++){ S0+=spart[w][t][0]; S1+=spart[w][t][1]; S2+=spart[w][t][2]; S3+=spart[w][t][3]; }
      const float inv=0.015625f;
      float mu_i=S0*inv, mu_e=S2*inv;
      float r_i=rsqrtf(fmaf(S1,inv,-mu_i*mu_i)+1e-5f);
      float r_e=rsqrtf(fmaf(S3,inv,-mu_e*mu_e)+1e-5f);
      params[t][0]=mu_i; params[t][1]=r_i; params[t][2]=mu_e; params[t][3]=r_e;
    }
    __syncthreads();
    #pragma unroll
    for (int j=0;j<8;j++){
      float4 pr = *(const float4*)&params[pg*8+j][0];
      float a0=(A0[j]-pr.x)*pr.y, a1=(A1[j]-pr.x)*pr.y;
      float c0f=(B0[j]-pr.z)*pr.w, c1f=(B1[j]-pr.z)*pr.w;
      float n0 = fmaf(a0, wi0, fmaf(c0f, we0, bs0));
      float n1 = fmaf(a1, wi1, fmaf(c1f, we1, bs1));
      *(u32*)&SB[(pg*8+j)*136 + ch0] = packbf2(n0, n1);
    }
    __syncthreads();
    float4v acc1[4];
    #pragma unroll
    for (int nj=0;nj<4;nj++) acc1[nj]=(float4v)0.f;
    const int px_row = wave*16 + l15;
    #pragma unroll
    for (int ks=0;ks<2;ks++){
      const int off = ks*32 + quad*8;
      short8 af = *(const short8*)&SB[px_row*136 + off];
      #pragma unroll
      for (int nj=0;nj<4;nj++){
        short8 bw = *(const short8*)&PcL[(nj*16+l15)*72 + off];
        acc1[nj] = __builtin_amdgcn_mfma_f32_16x16x32_bf16(af, bw, acc1[nj], 0,0,0);
      }
    }
    float s[4], sq[4];
    #pragma unroll
    for (int j=0;j<4;j++){
      s[j] = acc1[0][j]+acc1[1][j]+acc1[2][j]+acc1[3][j];
      sq[j] = acc1[0][j]*acc1[0][j];
      sq[j] = fmaf(acc1[1][j],acc1[1][j],sq[j]);
      sq[j] = fmaf(acc1[2][j],acc1[2][j],sq[j]);
      sq[j] = fmaf(acc1[3][j],acc1[3][j],sq[j]);
    }
    #pragma unroll
    for (int m=1;m<=8;m<<=1)
      #pragma unroll
      for (int j=0;j<4;j++){ s[j]+=__shfl_xor(s[j],m); sq[j]+=__shfl_xor(sq[j],m); }
    float muj[4], rj[4];
    #pragma unroll
    for (int j=0;j<4;j++){
      muj[j]=s[j]*0.015625f;
      rj[j]=rsqrtf(fmaf(sq[j],0.015625f,-muj[j]*muj[j])+1e-5f);
    }
    __syncthreads();
    #pragma unroll
    for (int nj=0;nj<4;nj++)
      #pragma unroll
      for (int j=0;j<4;j++){
        float tv = (acc1[nj][j]-muj[j])*rj[j];
        tv = fmaf(tv, w1r[nj], b1r[nj]);
        SB[(wave*16+quad*4+j)*136 + nj*16+l15] = f2bf(tv);
      }
    __syncthreads();
    float4v accF[8];
    #pragma unroll
    for (int nh=0;nh<8;nh++) accF[nh]=(float4v)0.f;
    #pragma unroll
    for (int ks=0;ks<2;ks++){
      const int off = ks*32+quad*8;
      short8 af = *(const short8*)&SB[px_row*136 + off];
      #pragma unroll
      for (int nh=0;nh<8;nh++){
        short8 bw = *(const short8*)&fc1L[(nh*16+l15)*72 + off];
        accF[nh] = __builtin_amdgcn_mfma_f32_16x16x32_bf16(af, bw, accF[nh], 0,0,0);
      }
    }
    __syncthreads();
    #pragma unroll
    for (int nh=0;nh<8;nh++){
      float bb = b1L[nh*16+l15];
      #pragma unroll
      for (int j=0;j<4;j++){
        float v = accF[nh][j] + bb;
        float g = 0.5f*v*(1.0f + erff(v*0.70710678118654752f));
        SB[(wave*16+quad*4+j)*136 + nh*16+l15] = f2bf(g);
      }
    }
    __syncthreads();
    float4v accO[4];
    #pragma unroll
    for (int nj=0;nj<4;nj++) accO[nj]=(float4v)0.f;
    #pragma unroll
    for (int ks=0;ks<4;ks++){
      const int off = ks*32+quad*8;
      short8 ag = *(const short8*)&SB[px_row*136 + off];
      #pragma unroll
      for (int nj=0;nj<4;nj++){
        short8 bw = *(const short8*)&fc2L[(nj*16+l15)*136 + off];
        accO[nj] = __builtin_amdgcn_mfma_f32_16x16x32_bf16(ag, bw, accO[nj], 0,0,0);
      }
    }
    #pragma unroll
    for (int nj=0;nj<4;nj++){
      float bb = b2L[nj*16+l15];
      int r = nj*16+l15;
      #pragma unroll
      for (int j=0;j<4;j++){
        int px = p0 + wave*16 + quad*4 + j;
        float val = acc1[nj][j] + accO[nj][j] + bb;
        size_t oi = obase + (size_t)(b*64 + r)*HW + px;
        if (f32) ((float*)outp)[oi] = val;
        else ((u16*)outp)[oi] = f2bf(val);
      }
    }
    __syncthreads();
  }
}

// ---------------------------------------------------------------------------
// K3 differential branch: od = P_id @ n_i + P_ed @ n_e, then LN/FFN/residual
// ---------------------------------------------------------------------------
__global__ __launch_bounds__(256) void k3_diff(
    const void* __restrict__ img, const void* __restrict__ evt,
    const u16* __restrict__ lniw, const u16* __restrict__ lnib,
    const u16* __restrict__ lnew, const u16* __restrict__ lneb,
    const u16* __restrict__ ln2w, const u16* __restrict__ ln2b,
    const u16* __restrict__ fc1w, const u16* __restrict__ fc1b,
    const u16* __restrict__ fc2w, const u16* __restrict__ fc2b,
    const float* __restrict__ Pmat, void* __restrict__ outp, size_t obase)
{
  __shared__ u16 fc1L[128*72];
  __shared__ u16 fc2L[64*136];
  __shared__ u16 PiL[64*72];
  __shared__ u16 PeL[64*72];
  __shared__ u16 N2L[64*144];
  __shared__ float spart[4][64][4];
  __shared__ float params[64][4];
  __shared__ float b1L[128];
  __shared__ float b2L[64];
  __shared__ int s_cnt;

  const int t = threadIdx.x;
  const bool f32 = detect_f32(img, t, &s_cnt);
  const u16* imgb = (const u16*)img; const float* imgf = (const float*)img;
  const u16* evtb = (const u16*)evt; const float* evtf = (const float*)evt;

  const int b = blockIdx.x >> 6;
  const int P0 = (blockIdx.x & 63) * 1024;
  const int chg = t >> 3, pg = t & 7, ch0 = chg*2;
  const int wave = t >> 6, lane = t & 63, l15 = lane & 15, quad = lane >> 4;

  { int row = t >> 1, c0 = (t & 1)*32;
    const uint4* s = (const uint4*)(fc1w + row*64 + c0);
    uint4* d = (uint4*)&fc1L[row*72 + c0];
    d[0]=s[0]; d[1]=s[1]; d[2]=s[2]; d[3]=s[3]; }
  { int row = t >> 2, c0 = (t & 3)*32;
    const uint4* s = (const uint4*)(fc2w + row*128 + c0);
    uint4* d = (uint4*)&fc2L[row*136 + c0];
    d[0]=s[0]; d[1]=s[1]; d[2]=s[2]; d[3]=s[3]; }
  { int row = t >> 2, c0 = (t & 3)*16;
    const float* si_ = Pmat + ((size_t)1*NBATCH + b)*4096 + row*64 + c0;
    const float* se_ = Pmat + ((size_t)2*NBATCH + b)*4096 + row*64 + c0;
    u32 u[8];
    #pragma unroll
    for (int i=0;i<8;i++) u[i] = packbf2(si_[2*i], si_[2*i+1]);
    uint4* d = (uint4*)&PiL[row*72 + c0];
    d[0] = make_uint4(u[0],u[1],u[2],u[3]); d[1] = make_uint4(u[4],u[5],u[6],u[7]);
    #pragma unroll
    for (int i=0;i<8;i++) u[i] = packbf2(se_[2*i], se_[2*i+1]);
    uint4* d2 = (uint4*)&PeL[row*72 + c0];
    d2[0] = make_uint4(u[0],u[1],u[2],u[3]); d2[1] = make_uint4(u[4],u[5],u[6],u[7]); }
  if (t < 128) b1L[t] = bf2f(fc1b[t]);
  if (t < 64)  b2L[t] = bf2f(fc2b[t]);

  float wi0=bf2f(lniw[ch0]), wi1=bf2f(lniw[ch0+1]);
  float bi0=bf2f(lnib[ch0]), bi1=bf2f(lnib[ch0+1]);
  float we0=bf2f(lnew[ch0]), we1=bf2f(lnew[ch0+1]);
  float be0=bf2f(lneb[ch0]), be1=bf2f(lneb[ch0+1]);
  float w1r[4], b1r[4];
  #pragma unroll
  for (int nj=0;nj<4;nj++){ w1r[nj]=bf2f(ln2w[nj*16+l15]); b1r[nj]=bf2f(ln2b[nj*16+l15]); }
  __syncthreads();

  const size_t base_i = (size_t)(b*64 + ch0)*HW;
  for (int it=0; it<16; ++it){
    const int p0 = P0 + it*64;
    float A0[8], A1[8], B0[8], B1[8];
    ld8(imgb, imgf, base_i + p0 + pg*8, f32, A0);
    ld8(imgb, imgf, base_i + HW + p0 + pg*8, f32, A1);
    ld8(evtb, evtf, base_i + p0 + pg*8, f32, B0);
    ld8(evtb, evtf, base_i + HW + p0 + pg*8, f32, B1);
    float si[8], sii[8], se[8], see[8];
    #pragma unroll
    for (int j=0;j<8;j++){
      float xi0=A0[j], xi1=A1[j], xe0=B0[j], xe1=B1[j];
      si[j]=xi0+xi1; sii[j]=fmaf(xi0,xi0,xi1*xi1);
      se[j]=xe0+xe1; see[j]=fmaf(xe0,xe0,xe1*xe1);
    }
    #pragma unroll
    for (int m=8;m<=32;m<<=1)
      #pragma unroll
      for (int j=0;j<8;j++){
        si[j]+=__shfl_xor(si[j],m); sii[j]+=__shfl_xor(sii[j],m);
        se[j]+=__shfl_xor(se[j],m); see[j]+=__shfl_xor(see[j],m);
      }
    if ((chg&7)==0){
      #pragma unroll
      for (int j=0;j<8;j++){
        spart[wave][pg*8+j][0]=si[j]; spart[wave][pg*8+j][1]=sii[j];
        spart[wave][pg*8+j][2]=se[j]; spart[wave][pg*8+j][3]=see[j];
      }
    }
    __syncthreads();
    if (t<64){
      float S0=0,S1=0,S2=0,S3=0;
      #pragma unroll
      for (int w=0;w<4;w++){ S0+=spart[w][t][0]; S1+=spart[w][t][1]; S2+=spart[w][t][2]; S3+=spart[w][t][3]; }
      const float inv=0.015625f;
      float mu_i=S0*inv, mu_e=S2*inv;
      float r_i=rsqrtf(fmaf(S1,inv,-mu_i*mu_i)+1e-5f);
      float r_e=rsqrtf(fmaf(S3,inv,-mu_e*mu_e)+1e-5f);
      params[t][0]=mu_i; params[t][1]=r_i; params[t][2]=mu_e; params[t][3]=r_e;
    }
    __syncthreads();
    #pragma unroll
    for (int j=0;j<8;j++){
      float4 pr = *(const float4*)&params[pg*8+j][0];
      float a0=(A0[j]-pr.x)*pr.y, a1=(A1[j]-pr.x)*pr.y;
      float c0f=(B0[j]-pr.z)*pr.w, c1f=(B1[j]-pr.z)*pr.w;
      *(u32*)&N2L[(pg*8+j)*144 + ch0]      = packbf2(fmaf(a0,wi0,bi0), fmaf(a1,wi1,bi1));
      *(u32*)&N2L[(pg*8+j)*144 + 72 + ch0] = packbf2(fmaf(c0f,we0,be0), fmaf(c1f,we1,be1));
    }
    __syncthreads();
    float4v acc1[4];
    #pragma unroll
    for (int nj=0;nj<4;nj++) acc1[nj]=(float4v)0.f;
    const int px_row = wave*16 + l15;
    #pragma unroll
    for (int ks=0;ks<2;ks++){
      const int off = ks*32 + quad*8;
      short8 ai = *(const short8*)&N2L[px_row*144 + off];
      short8 ae = *(const short8*)&N2L[px_row*144 + 72 + off];
      #pragma unroll
      for (int nj=0;nj<4;nj++){
        short8 bwi = *(const short8*)&PiL[(nj*16+l15)*72 + off];
        acc1[nj] = __builtin_amdgcn_mfma_f32_16x16x32_bf16(ai, bwi, acc1[nj], 0,0,0);
        short8 bwe = *(const short8*)&PeL[(nj*16+l15)*72 + off];
        acc1[nj] = __builtin_amdgcn_mfma_f32_16x16x32_bf16(ae, bwe, acc1[nj], 0,0,0);
      }
    }
    float s[4], sq[4];
    #pragma unroll
    for (int j=0;j<4;j++){
      s[j] = acc1[0][j]+acc1[1][j]+acc1[2][j]+acc1[3][j];
      sq[j] = acc1[0][j]*acc1[0][j];
      sq[j] = fmaf(acc1[1][j],acc1[1][j],sq[j]);
      sq[j] = fmaf(acc1[2][j],acc1[2][j],sq[j]);
      sq[j] = fmaf(acc1[3][j],acc1[3][j],sq[j]);
    }
    #pragma unroll
    for (int m=1;m<=8;m<<=1)
      #pragma unroll
      for (int j=0;j<4;j++){ s[j]+=__shfl_xor(s[j],m); sq[j]+=__shfl_xor(sq[j],m); }
    float muj[4], rj[4];
    #pragma unroll
    for (int j=0;j<4;j++){
      muj[j]=s[j]*0.015625f;
      rj[j]=rsqrtf(fmaf(sq[j],0.015625f,-muj[j]*muj[j])+1e-5f);
    }
    __syncthreads();
    #pragma unroll
    for (int nj=0;nj<4;nj++)
      #pragma unroll
      for (int j=0;j<4;j++){
        float tv = (acc1[nj][j]-muj[j])*rj[j];
        tv = fmaf(tv, w1r[nj], b1r[nj]);
        N2L[(wave*16+quad*4+j)*144 + nj*16+l15] = f2bf(tv);
      }
    __syncthreads();
    float4v accF[8];
    #pragma unroll
    for (int nh=0;nh<8;nh++) accF[nh]=(float4v)0.f;
    #pragma unroll
    for (int ks=0;ks<2;ks++){
      const int off = ks*32+quad*8;
      short8 af = *(const short8*)&N2L[px_row*144 + off];
      #pragma unroll
      for (int nh=0;nh<8;nh++){
        short8 bw = *(const short8*)&fc1L[(nh*16+l15)*72 + off];
        accF[nh] = __builtin_amdgcn_mfma_f32_16x16x32_bf16(af, bw, accF[nh], 0,0,0);
      }
    }
    __syncthreads();
    #pragma unroll
    for (int nh=0;nh<8;nh++){
      float bb = b1L[nh*16+l15];
      #pragma unroll
      for (int j=0;j<4;j++){
        float v = accF[nh][j] + bb;
        float g = 0.5f*v*(1.0f + erff(v*0.70710678118654752f));
        N2L[(wave*16+quad*4+j)*144 + nh*16+l15] = f2bf(g);
      }
    }
    __syncthreads();
    float4v accO[4];
    #pragma unroll
    for (int nj=0;nj<4;nj++) accO[nj]=(float4v)0.f;
    #pragma unroll
    for (int ks=0;ks<4;ks++){
      const int off = ks*32+quad*8;
      short8 ag = *(const short8*)&N2L[px_row*144 + off];
      #pragma unroll
      for (int nj=0;nj<4;nj++){
        short8 bw = *(const short8*)&fc2L[(nj*16+l15)*136 + off];
        accO[nj] = __builtin_amdgcn_mfma_f32_16x16x32_bf16(ag, bw, accO[nj], 0,0,0);
      }
    }
    #pragma unroll
    for (int nj=0;nj<4;nj++){
      float bb = b2L[nj*16+l15];
      int r = nj*16+l15;
      #pragma unroll
      for (int j=0;j<4;j++){
        int px = p0 + wave*16 + quad*4 + j;
        float val = acc1[nj][j] + accO[nj][j] + bb;
        size_t oi = obase + (size_t)(b*64 + r)*HW + px;
        if (f32) ((float*)outp)[oi] = val;
        else ((u16*)outp)[oi] = f2bf(val);
      }
    }
    __syncthreads();
  }
}

extern "C" void kernel_launch(void* const* d_in, const int* in_sizes, int n_in,
                              void* d_out, int out_size, void* d_ws, size_t ws_size,
                              hipStream_t stream)
{
  const void* img = d_in[0];
  const void* evt = d_in[1];
  float* ws = (float*)d_ws;
  u16* wc = (u16*)(ws + OFF_WC);
  #define SLOT(i) (wc + (size_t)((i)-2)*8192)

  hipMemsetAsync(ws, 0, 131072*sizeof(float), stream);
  convert_all<<<dim3(30), dim3(256), 0, stream>>>(img,
      d_in[2], d_in[3], d_in[4], d_in[5], d_in[6], d_in[7], d_in[8], d_in[9],
      d_in[10], d_in[11], d_in[12], d_in[13], d_in[14], d_in[15], d_in[16], d_in[17],
      d_in[18], d_in[19], d_in[20], d_in[21], d_in[22], d_in[23], d_in[24], d_in[25],
      d_in[26], d_in[27], d_in[28], d_in[29], d_in[30], d_in[31], wc);
  k1_cov<<<dim3(256), dim3(256), 0, stream>>>(img, evt,
      SLOT(10), SLOT(11), SLOT(12), SLOT(13), SLOT(14), SLOT(15), SLOT(16), SLOT(17), ws);
  p2a<<<dim3(40), dim3(256), 0, stream>>>(SLOT(2), SLOT(3), SLOT(6), SLOT(7), ws);
  p2b<<<dim3(4), dim3(256), 0, stream>>>(ws, SLOT(2), SLOT(3), SLOT(6), SLOT(7),
      SLOT(4), SLOT(8), SLOT(5), SLOT(9));
  p2c<<<dim3(12), dim3(256), 0, stream>>>(SLOT(30), SLOT(31), ws);
  k3_common<<<dim3(256), dim3(256), 0, stream>>>(img, evt,
      SLOT(10), SLOT(11), SLOT(12), SLOT(13), SLOT(18), SLOT(19),
      SLOT(22), SLOT(23), SLOT(24), SLOT(25), ws + OFF_P, d_out, (size_t)0);
  k3_diff<<<dim3(256), dim3(256), 0, stream>>>(img, evt,
      SLOT(10), SLOT(11), SLOT(12), SLOT(13), SLOT(20), SLOT(21),
      SLOT(26), SLOT(27), SLOT(28), SLOT(29), ws + OFF_P, d_out, (size_t)16777216);
  #undef SLOT
}

// Round 4
// 634.441 us; speedup vs baseline: 1.2013x; 1.2013x over previous
//
#include <hip/hip_runtime.h>
#include <math.h>

typedef unsigned int u32;
typedef unsigned short u16;
typedef __attribute__((ext_vector_type(8))) short short8;
typedef __attribute__((ext_vector_type(4))) float float4v;

#define NBATCH 4
#define HW 65536

// ws layout (floats)
#define OFF_COV 0        // cov[8][B][64][64]   131072 floats  [0,131072)
#define OFF_T   131072   // T[10][B][64][64]    163840 floats  [131072,294912)
#define OFF_M   294912   // M[3][B][64][64]      49152 floats  [294912,344064)
#define OFF_P   344064   // P[3][B][64][64]      49152 floats  [344064,393216)
#define OFF_WC  393216   // canonical bf16 weights: 30 x 8192 u16 = 122880 floats
#define OFF_PAR 516096   // per-px LN stats {mu_i,r_i,mu_e,r_e}: 262144*4 floats
#define WS_NEED ((size_t)(OFF_PAR + 1048576) * 4)

__device__ inline float bf2f(u16 h){ return __uint_as_float(((u32)h) << 16); }
__device__ inline u16 f2bf(float x){
  u32 u = __float_as_uint(x);
  u += 0x7fffu + ((u >> 16) & 1u);
  return (u16)(u >> 16);
}
__device__ inline u32 packbf2(float a, float b){
  return (u32)f2bf(a) | ((u32)f2bf(b) << 16);
}
__device__ inline float bfu(u32 u, int hi){
  return __uint_as_float(hi ? (u & 0xffff0000u) : (u << 16));
}

// Device-side dtype sniff: bf16 data has sane low-half bf16 exponents; fp32
// data's low 16 bits are mantissa noise. 256 threads vote.
__device__ inline bool detect_f32(const void* probe, int t, int* s_cnt){
  if (t == 0) *s_cnt = 0;
  __syncthreads();
  u32 w = ((const u32*)probe)[t & 255];
  u32 ex = (w >> 7) & 0xffu;
  if (!(ex >= 113u && ex <= 133u)) atomicAdd(s_cnt, 1);
  __syncthreads();
  return *s_cnt >= 128;
}

__device__ inline void ld8(const u16* pb, const float* pf, size_t idx, bool f32, float* o){
  if (f32){
    const float4 a = *(const float4*)(pf + idx);
    const float4 b = *(const float4*)(pf + idx + 4);
    o[0]=a.x; o[1]=a.y; o[2]=a.z; o[3]=a.w; o[4]=b.x; o[5]=b.y; o[6]=b.z; o[7]=b.w;
  } else {
    uint4 r = *(const uint4*)(pb + idx);
    const u32* p = (const u32*)&r;
    #pragma unroll
    for (int j=0;j<8;j++) o[j] = bfu(p[j>>1], j&1);
  }
}

__device__ inline void softmax16(float* l){
  float m = l[0];
  #pragma unroll
  for (int i=1;i<16;i++) m = fmaxf(m, l[i]);
  float s = 0.f;
  #pragma unroll
  for (int i=0;i<16;i++){ l[i] = __expf(l[i]-m); s += l[i]; }
  float r = 1.0f/s;
  #pragma unroll
  for (int i=0;i<16;i++) l[i] *= r;
}

// ---------------------------------------------------------------------------
// convert_all: canonicalize 30 weight tensors to bf16 slots (8192 u16 each)
// ---------------------------------------------------------------------------
__global__ __launch_bounds__(256) void convert_all(
    const void* img,
    const void* t0, const void* t1, const void* t2, const void* t3,
    const void* t4, const void* t5, const void* t6, const void* t7,
    const void* t8, const void* t9, const void* t10, const void* t11,
    const void* t12, const void* t13, const void* t14, const void* t15,
    const void* t16, const void* t17, const void* t18, const void* t19,
    const void* t20, const void* t21, const void* t22, const void* t23,
    const void* t24, const void* t25, const void* t26, const void* t27,
    const void* t28, const void* t29,
    u16* __restrict__ wc)
{
  __shared__ int s_cnt;
  const int t = threadIdx.x;
  const bool f32 = detect_f32(img, t, &s_cnt);
  const int sizes[30] = {4096,4096,4096,4,4096,4096,4096,4,
                         64,64,64,64,64,64,64,64,64,64,64,64,
                         8192,128,8192,64,8192,128,8192,64,4096,4096};
  const void* srcs[30] = {t0,t1,t2,t3,t4,t5,t6,t7,t8,t9,t10,t11,t12,t13,t14,
                          t15,t16,t17,t18,t19,t20,t21,t22,t23,t24,t25,t26,t27,t28,t29};
  const int id = blockIdx.x;
  const void* s = srcs[id];
  const int n = sizes[id];
  u16* d = wc + (size_t)id*8192;
  for (int j = t; j < n; j += 256)
    d[j] = f32 ? f2bf(((const float*)s)[j]) : ((const u16*)s)[j];
}

// ---------------------------------------------------------------------------
// K1: per-pixel LN of {img, evt, img+evt, img-evt} -> 8 covariance matrices.
// grid 512: b = blk>>7, px range (blk&127)*512, 8 iters of 64 px.
// Also stores per-px {mu_i,r_i,mu_e,r_e} fp32 to par[] when use_par (k3 reuses).
// ---------------------------------------------------------------------------
__global__ __launch_bounds__(256) void k1_cov(
    const void* __restrict__ img, const void* __restrict__ evt,
    const u16* __restrict__ lniw, const u16* __restrict__ lnib,
    const u16* __restrict__ lnew, const u16* __restrict__ lneb,
    const u16* __restrict__ lncw, const u16* __restrict__ lncb,
    const u16* __restrict__ lndw, const u16* __restrict__ lndb,
    float* __restrict__ cov, float* __restrict__ par, int use_par)
{
  __shared__ u16 NtL[4*64*72];
  __shared__ float spart[4][64][5];
  __shared__ float params[64][8];
  __shared__ int s_cnt;

  const int t = threadIdx.x;
  const bool f32 = detect_f32(img, t, &s_cnt);
  const u16* imgb = (const u16*)img; const float* imgf = (const float*)img;
  const u16* evtb = (const u16*)evt; const float* evtf = (const float*)evt;

  const int b = blockIdx.x >> 7;
  const int P0 = (blockIdx.x & 127) * 512;
  const int chg = t >> 3, pg = t & 7, ch0 = chg*2;
  const int wave = t >> 6, lane = t & 63, l15 = lane & 15, quad = lane >> 4;

  float wi0=bf2f(lniw[ch0]), wi1=bf2f(lniw[ch0+1]);
  float bi0=bf2f(lnib[ch0]), bi1=bf2f(lnib[ch0+1]);
  float we0=bf2f(lnew[ch0]), we1=bf2f(lnew[ch0+1]);
  float be0=bf2f(lneb[ch0]), be1=bf2f(lneb[ch0+1]);
  float wc0=bf2f(lncw[ch0]), wc1=bf2f(lncw[ch0+1]);
  float bc0=bf2f(lncb[ch0]), bc1=bf2f(lncb[ch0+1]);
  float wd0=bf2f(lndw[ch0]), wd1=bf2f(lndw[ch0+1]);
  float bd0=bf2f(lndb[ch0]), bd1=bf2f(lndb[ch0+1]);

  int va1, vb1, va2, vb2;
  if (wave == 0){ va1=2; vb1=2; va2=2; vb2=0; }       // cc, ci
  else if (wave == 1){ va1=2; vb1=1; va2=0; vb2=0; }  // ce, ii
  else if (wave == 2){ va1=3; vb1=3; va2=3; vb2=0; }  // dd, di
  else { va1=3; vb1=1; va2=1; vb2=1; }                // de, ee

  float4v acc0[4][4], acc1v[4][4];
  #pragma unroll
  for (int i=0;i<4;i++)
    #pragma unroll
    for (int j=0;j<4;j++){ acc0[i][j]=(float4v)0.f; acc1v[i][j]=(float4v)0.f; }

  const size_t base_i = (size_t)(b*64 + ch0) * HW;

  for (int it = 0; it < 8; ++it){
    const int p0 = P0 + it*64;
    float A0[8], A1[8], B0[8], B1[8];
    ld8(imgb, imgf, base_i + p0 + pg*8, f32, A0);
    ld8(imgb, imgf, base_i + HW + p0 + pg*8, f32, A1);
    ld8(evtb, evtf, base_i + p0 + pg*8, f32, B0);
    ld8(evtb, evtf, base_i + HW + p0 + pg*8, f32, B1);

    float si[8], sii[8], se[8], see[8], sie[8];
    #pragma unroll
    for (int j=0;j<8;j++){
      float xi0=A0[j], xi1=A1[j], xe0=B0[j], xe1=B1[j];
      si[j]  = xi0 + xi1;
      sii[j] = fmaf(xi0, xi0, xi1*xi1);
      se[j]  = xe0 + xe1;
      see[j] = fmaf(xe0, xe0, xe1*xe1);
      sie[j] = fmaf(xi0, xe0, xi1*xe1);
    }
    #pragma unroll
    for (int m=8; m<=32; m<<=1){
      #pragma unroll
      for (int j=0;j<8;j++){
        si[j]  += __shfl_xor(si[j],  m);
        sii[j] += __shfl_xor(sii[j], m);
        se[j]  += __shfl_xor(se[j],  m);
        see[j] += __shfl_xor(see[j], m);
        sie[j] += __shfl_xor(sie[j], m);
      }
    }
    if ((chg & 7) == 0){
      #pragma unroll
      for (int j=0;j<8;j++){
        spart[wave][pg*8+j][0]=si[j];  spart[wave][pg*8+j][1]=sii[j];
        spart[wave][pg*8+j][2]=se[j];  spart[wave][pg*8+j][3]=see[j];
        spart[wave][pg*8+j][4]=sie[j];
      }
    }
    __syncthreads();
    if (t < 64){
      float S0=0,S1=0,S2=0,S3=0,S4=0;
      #pragma unroll
      for (int w=0;w<4;w++){
        S0+=spart[w][t][0]; S1+=spart[w][t][1]; S2+=spart[w][t][2];
        S3+=spart[w][t][3]; S4+=spart[w][t][4];
      }
      const float inv = 0.015625f;
      float mu_i=S0*inv, mu_e=S2*inv;
      float r_i = rsqrtf(fmaf(S1,inv,-mu_i*mu_i)+1e-5f);
      float r_e = rsqrtf(fmaf(S3,inv,-mu_e*mu_e)+1e-5f);
      float mu_c=mu_i+mu_e, mu_d=mu_i-mu_e;
      float r_c = rsqrtf((S1+2.f*S4+S3)*inv - mu_c*mu_c + 1e-5f);
      float r_d = rsqrtf((S1-2.f*S4+S3)*inv - mu_d*mu_d + 1e-5f);
      params[t][0]=mu_i; params[t][1]=r_i; params[t][2]=mu_e; params[t][3]=r_e;
      params[t][4]=mu_c; params[t][5]=r_c; params[t][6]=mu_d; params[t][7]=r_d;
      if (use_par){
        float4 pv; pv.x=mu_i; pv.y=r_i; pv.z=mu_e; pv.w=r_e;
        *(float4*)(par + ((size_t)b*HW + p0 + t)*4) = pv;
      }
    }
    __syncthreads();
    u32 un[4][2][4];
    #pragma unroll
    for (int jj=0;jj<4;jj++){
      float4 pA0 = *(const float4*)&params[pg*8+jj*2][0];
      float4 pB0 = *(const float4*)&params[pg*8+jj*2][4];
      float4 pA1 = *(const float4*)&params[pg*8+jj*2+1][0];
      float4 pB1 = *(const float4*)&params[pg*8+jj*2+1][4];
      float xiA0=A0[2*jj], xiA1=A1[2*jj], xeA0=B0[2*jj], xeA1=B1[2*jj];
      float xiB0=A0[2*jj+1], xiB1=A1[2*jj+1], xeB0=B0[2*jj+1], xeB1=B1[2*jj+1];
      un[0][0][jj] = packbf2(fmaf((xiA0-pA0.x)*pA0.y, wi0, bi0), fmaf((xiB0-pA1.x)*pA1.y, wi0, bi0));
      un[0][1][jj] = packbf2(fmaf((xiA1-pA0.x)*pA0.y, wi1, bi1), fmaf((xiB1-pA1.x)*pA1.y, wi1, bi1));
      un[1][0][jj] = packbf2(fmaf((xeA0-pA0.z)*pA0.w, we0, be0), fmaf((xeB0-pA1.z)*pA1.w, we0, be0));
      un[1][1][jj] = packbf2(fmaf((xeA1-pA0.z)*pA0.w, we1, be1), fmaf((xeB1-pA1.z)*pA1.w, we1, be1));
      float xcA0=xiA0+xeA0, xcA1=xiA1+xeA1, xcB0=xiB0+xeB0, xcB1=xiB1+xeB1;
      un[2][0][jj] = packbf2(fmaf((xcA0-pB0.x)*pB0.y, wc0, bc0), fmaf((xcB0-pB1.x)*pB1.y, wc0, bc0));
      un[2][1][jj] = packbf2(fmaf((xcA1-pB0.x)*pB0.y, wc1, bc1), fmaf((xcB1-pB1.x)*pB1.y, wc1, bc1));
      float xdA0=xiA0-xeA0, xdA1=xiA1-xeA1, xdB0=xiB0-xeB0, xdB1=xiB1-xeB1;
      un[3][0][jj] = packbf2(fmaf((xdA0-pB0.z)*pB0.w, wd0, bd0), fmaf((xdB0-pB1.z)*pB1.w, wd0, bd0));
      un[3][1][jj] = packbf2(fmaf((xdA1-pB0.z)*pB0.w, wd1, bd1), fmaf((xdB1-pB1.z)*pB1.w, wd1, bd1));
    }
    #pragma unroll
    for (int v=0; v<4; v++){
      *(uint4*)&NtL[(v*64 + ch0  )*72 + pg*8] = make_uint4(un[v][0][0],un[v][0][1],un[v][0][2],un[v][0][3]);
      *(uint4*)&NtL[(v*64 + ch0+1)*72 + pg*8] = make_uint4(un[v][1][0],un[v][1][1],un[v][1][2],un[v][1][3]);
    }
    __syncthreads();
    #pragma unroll
    for (int ks=0; ks<2; ks++){
      const int off = ks*32 + quad*8;
      short8 A1f[4], B1f[4], A2f[4], B2f[4];
      #pragma unroll
      for (int mi=0;mi<4;mi++){
        A1f[mi] = *(const short8*)&NtL[(va1*64 + mi*16 + l15)*72 + off];
        B1f[mi] = *(const short8*)&NtL[(vb1*64 + mi*16 + l15)*72 + off];
        A2f[mi] = *(const short8*)&NtL[(va2*64 + mi*16 + l15)*72 + off];
        B2f[mi] = *(const short8*)&NtL[(vb2*64 + mi*16 + l15)*72 + off];
      }
      #pragma unroll
      for (int mi=0;mi<4;mi++)
        #pragma unroll
        for (int nj=0;nj<4;nj++){
          acc0[mi][nj]  = __builtin_amdgcn_mfma_f32_16x16x32_bf16(A1f[mi], B1f[nj], acc0[mi][nj], 0,0,0);
          acc1v[mi][nj] = __builtin_amdgcn_mfma_f32_16x16x32_bf16(A2f[mi], B2f[nj], acc1v[mi][nj], 0,0,0);
        }
    }
    // no end-of-loop barrier: next iter's NtL write is behind 2 barriers
  }
  float* c0 = cov + ((size_t)(wave*2 + 0)*NBATCH + b)*4096;
  float* c1 = cov + ((size_t)(wave*2 + 1)*NBATCH + b)*4096;
  #pragma unroll
  for (int mi=0;mi<4;mi++)
    #pragma unroll
    for (int nj=0;nj<4;nj++){
      int row0 = mi*16 + quad*4, col = nj*16 + l15;
      #pragma unroll
      for (int r=0;r<4;r++){
        atomicAdd(&c0[(row0+r)*64 + col], acc0[mi][nj][r]);
        atomicAdd(&c1[(row0+r)*64 + col], acc1v[mi][nj][r]);
      }
    }
}

// ---------------------------------------------------------------------------
// P2a: T = W @ C  (10 products per batch)
// ---------------------------------------------------------------------------
__global__ __launch_bounds__(256) void p2a(
    const u16* __restrict__ Wq_c, const u16* __restrict__ Wk_c,
    const u16* __restrict__ Wq_d, const u16* __restrict__ Wk_d,
    float* __restrict__ ws)
{
  __shared__ float WL[64][65];
  __shared__ float CL[64][64];
  const int t = threadIdx.x;
  const int b = blockIdx.x & 3;
  const int which = blockIdx.x >> 2;
  int wsel, csel;
  switch (which){
    case 0: wsel=0; csel=0; break;
    case 1: wsel=1; csel=3; break;
    case 2: wsel=1; csel=7; break;
    case 3: wsel=2; csel=4; break;
    case 4: wsel=3; csel=3; break;
    case 5: wsel=3; csel=7; break;
    case 6: wsel=0; csel=1; break;
    case 7: wsel=0; csel=2; break;
    case 8: wsel=2; csel=5; break;
    default: wsel=2; csel=6; break;
  }
  const u16* W = (wsel==0)? Wq_c : (wsel==1)? Wk_c : (wsel==2)? Wq_d : Wk_d;
  const float* Cm = ws + ((size_t)csel*NBATCH + b)*4096;
  { int r = t>>2, c0 = (t&3)*16;
    #pragma unroll
    for (int i=0;i<16;i++) WL[r][c0+i] = bf2f(W[r*64 + c0 + i]);
    const float4* s = (const float4*)(Cm + r*64 + c0);
    float4* d = (float4*)&CL[r][c0];
    d[0]=s[0]; d[1]=s[1]; d[2]=s[2]; d[3]=s[3]; }
  __syncthreads();
  const int r = t>>2, k0 = (t&3)*16;
  float a[16];
  #pragma unroll
  for (int i=0;i<16;i++) a[i]=0.f;
  for (int m=0;m<64;m++){
    float wv = WL[r][m];
    #pragma unroll
    for (int i=0;i<16;i++) a[i] = fmaf(wv, CL[m][k0+i], a[i]);
  }
  float* o = ws + OFF_T + ((size_t)which*NBATCH + b)*4096 + r*64 + k0;
  #pragma unroll
  for (int i=0;i<16;i++) o[i] = a[i];
}

// ---------------------------------------------------------------------------
// P2b: norms, Gram blocks, softmax, A, M = blockdiag(A)@Wv
// ---------------------------------------------------------------------------
__global__ __launch_bounds__(256) void p2b(
    float* __restrict__ ws,
    const u16* __restrict__ Wq_c, const u16* __restrict__ Wk_c,
    const u16* __restrict__ Wq_d, const u16* __restrict__ Wk_d,
    const u16* __restrict__ Wv_c, const u16* __restrict__ Wv_d,
    const u16* __restrict__ temp_c, const u16* __restrict__ temp_d)
{
  const int b = blockIdx.x, t = threadIdx.x;
  __shared__ float rn[6][64];
  __shared__ float GLs[4][64][16];
  __shared__ float AL[3][64][16];
  const float* T = ws + OFF_T;
  {
    int s = t>>6, c = t&63;
    const float* Tp = T + ((size_t)s*NBATCH + b)*4096 + c*64;
    const u16* Wp = (s==0)? Wq_c : (s==3)? Wq_d : Wk_c;
    float acc=0;
    for (int k=0;k<64;k++) acc = fmaf(Tp[k], bf2f(Wp[c*64+k]), acc);
    rn[s][c] = 1.0f/fmaxf(sqrtf(fmaxf(acc,0.f)), 1e-12f);
    if (t < 128){
      int s2 = 4 + (t>>6);
      const float* Tp2 = T + ((size_t)s2*NBATCH + b)*4096 + c*64;
      float acc2=0;
      for (int k=0;k<64;k++) acc2 = fmaf(Tp2[k], bf2f(Wk_d[c*64+k]), acc2);
      rn[s2][c] = 1.0f/fmaxf(sqrtf(fmaxf(acc2,0.f)), 1e-12f);
    }
  }
  #pragma unroll 1
  for (int i=0;i<16;i++){
    int e = t*16 + i;
    int s = e >> 10, c = (e>>4)&63, dl = e&15, d = (c&~15)+dl;
    const float* Tp = T + ((size_t)(6+s)*NBATCH + b)*4096 + c*64;
    const u16* Wp = ((s<2)? Wk_c : Wk_d) + d*64;
    float acc=0;
    for (int j=0;j<64;j++) acc = fmaf(Tp[j], bf2f(Wp[j]), acc);
    GLs[s][c][dl] = acc;
  }
  __syncthreads();
  if (t < 192){
    int set = t>>6, c = t&63, h = c>>4, cb = c&~15;
    if (set == 0){
      float tc = bf2f(temp_c[h]);
      float rq = rn[0][c];
      float l1[16], l2[16];
      #pragma unroll
      for (int dl=0;dl<16;dl++){
        l1[dl] = GLs[0][c][dl]*rq*rn[1][cb+dl]*tc;
        l2[dl] = GLs[1][c][dl]*rq*rn[2][cb+dl]*tc;
      }
      softmax16(l1); softmax16(l2);
      #pragma unroll
      for (int dl=0;dl<16;dl++) AL[0][c][dl] = l1[dl]*l2[dl];
    } else {
      float td = bf2f(temp_d[h]);
      float rq = rn[3][c];
      int gi = (set==1)? 2 : 3;
      int rk = (set==1)? 4 : 5;
      float l[16];
      #pragma unroll
      for (int dl=0;dl<16;dl++) l[dl] = GLs[gi][c][dl]*rq*rn[rk][cb+dl]*td;
      softmax16(l);
      #pragma unroll
      for (int dl=0;dl<16;dl++) AL[set][c][dl] = l[dl];
    }
  }
  __syncthreads();
  for (int wsel=0; wsel<3; wsel++){
    const u16* Wv = (wsel==0)? Wv_c : Wv_d;
    #pragma unroll 1
    for (int i=0;i<16;i++){
      int e = t*16+i, c = e>>6, k = e&63, cb = c&~15;
      float acc=0;
      #pragma unroll
      for (int dl=0;dl<16;dl++) acc = fmaf(AL[wsel][c][dl], bf2f(Wv[(cb+dl)*64 + k]), acc);
      ws[OFF_M + ((size_t)wsel*NBATCH + b)*4096 + c*64 + k] = acc;
    }
  }
}

// ---------------------------------------------------------------------------
// P2c: P = proj @ M  (3 per batch)
// ---------------------------------------------------------------------------
__global__ __launch_bounds__(256) void p2c(
    const u16* __restrict__ proj1, const u16* __restrict__ proj2,
    float* __restrict__ ws)
{
  __shared__ float WL[64][65];
  __shared__ float CL[64][64];
  const int t = threadIdx.x;
  const int b = blockIdx.x & 3;
  const int which = blockIdx.x >> 2;
  const u16* W = (which==0)? proj1 : proj2;
  const float* Cm = ws + OFF_M + ((size_t)which*NBATCH + b)*4096;
  { int r = t>>2, c0 = (t&3)*16;
    #pragma unroll
    for (int i=0;i<16;i++) WL[r][c0+i] = bf2f(W[r*64 + c0 + i]);
    const float4* s = (const float4*)(Cm + r*64 + c0);
    float4* d = (float4*)&CL[r][c0];
    d[0]=s[0]; d[1]=s[1]; d[2]=s[2]; d[3]=s[3]; }
  __syncthreads();
  const int r = t>>2, k0 = (t&3)*16;
  float a[16];
  #pragma unroll
  for (int i=0;i<16;i++) a[i]=0.f;
  for (int m=0;m<64;m++){
    float wv = WL[r][m];
    #pragma unroll
    for (int i=0;i<16;i++) a[i] = fmaf(wv, CL[m][k0+i], a[i]);
  }
  float* o = ws + OFF_P + ((size_t)which*NBATCH + b)*4096 + r*64 + k0;
  #pragma unroll
  for (int i=0;i<16;i++) o[i] = a[i];
}

// ---------------------------------------------------------------------------
// K3 common: out = oc + FFN(LN(oc)), oc = P_c @ (n_i + n_e).
// grid 1024: b = blk>>8, px range (blk&255)*256, 4 iters of 64 px.
// use_par: per-px LN stats loaded from par[] (computed in k1) -> 2 barriers/iter.
// ---------------------------------------------------------------------------
__global__ __launch_bounds__(256) void k3_common(
    const void* __restrict__ img, const void* __restrict__ evt,
    const u16* __restrict__ lniw, const u16* __restrict__ lnib,
    const u16* __restrict__ lnew, const u16* __restrict__ lneb,
    const u16* __restrict__ ln1w, const u16* __restrict__ ln1b,
    const u16* __restrict__ fc1w, const u16* __restrict__ fc1b,
    const u16* __restrict__ fc2w, const u16* __restrict__ fc2b,
    const float* __restrict__ Pmat, void* __restrict__ outp, size_t obase,
    const float* __restrict__ par, int use_par)
{
  __shared__ u16 fc1L[128*72];
  __shared__ u16 fc2L[64*136];
  __shared__ u16 PcL[64*72];
  __shared__ u16 SB[64*136];
  __shared__ float spart[4][64][4];
  __shared__ float params[64][4];
  __shared__ float b1L[128];
  __shared__ float b2L[64];
  __shared__ int s_cnt;

  const int t = threadIdx.x;
  const bool f32 = detect_f32(img, t, &s_cnt);
  const u16* imgb = (const u16*)img; const float* imgf = (const float*)img;
  const u16* evtb = (const u16*)evt; const float* evtf = (const float*)evt;

  const int b = blockIdx.x >> 8;
  const int P0 = (blockIdx.x & 255) * 256;
  const int chg = t >> 3, pg = t & 7, ch0 = chg*2;
  const int wave = t >> 6, lane = t & 63, l15 = lane & 15, quad = lane >> 4;

  { int row = t >> 1, c0 = (t & 1)*32;
    const uint4* s = (const uint4*)(fc1w + row*64 + c0);
    uint4* d = (uint4*)&fc1L[row*72 + c0];
    d[0]=s[0]; d[1]=s[1]; d[2]=s[2]; d[3]=s[3]; }
  { int row = t >> 2, c0 = (t & 3)*32;
    const uint4* s = (const uint4*)(fc2w + row*128 + c0);
    uint4* d = (uint4*)&fc2L[row*136 + c0];
    d[0]=s[0]; d[1]=s[1]; d[2]=s[2]; d[3]=s[3]; }
  { int row = t >> 2, c0 = (t & 3)*16;
    const float* s = Pmat + (size_t)b*4096 + row*64 + c0;
    u32 u[8];
    #pragma unroll
    for (int i=0;i<8;i++) u[i] = packbf2(s[2*i], s[2*i+1]);
    uint4* d = (uint4*)&PcL[row*72 + c0];
    d[0] = make_uint4(u[0],u[1],u[2],u[3]);
    d[1] = make_uint4(u[4],u[5],u[6],u[7]); }
  if (t < 128) b1L[t] = bf2f(fc1b[t]);
  if (t < 64)  b2L[t] = bf2f(fc2b[t]);

  float wi0=bf2f(lniw[ch0]), wi1=bf2f(lniw[ch0+1]);
  float we0=bf2f(lnew[ch0]), we1=bf2f(lnew[ch0+1]);
  float bs0=bf2f(lnib[ch0]) + bf2f(lneb[ch0]);
  float bs1=bf2f(lnib[ch0+1]) + bf2f(lneb[ch0+1]);
  float w1r[4], b1r[4];
  #pragma unroll
  for (int nj=0;nj<4;nj++){ w1r[nj]=bf2f(ln1w[nj*16+l15]); b1r[nj]=bf2f(ln1b[nj*16+l15]); }
  __syncthreads();

  const size_t base_i = (size_t)(b*64 + ch0)*HW;
  for (int it=0; it<4; ++it){
    const int p0 = P0 + it*64;
    float A0[8], A1[8], B0[8], B1[8];
    ld8(imgb, imgf, base_i + p0 + pg*8, f32, A0);
    ld8(imgb, imgf, base_i + HW + p0 + pg*8, f32, A1);
    ld8(evtb, evtf, base_i + p0 + pg*8, f32, B0);
    ld8(evtb, evtf, base_i + HW + p0 + pg*8, f32, B1);

    if (use_par){
      const float4* pp = (const float4*)(par + ((size_t)b*HW + p0 + pg*8)*4);
      #pragma unroll
      for (int j=0;j<8;j++){
        float4 pr = pp[j];
        float a0=(A0[j]-pr.x)*pr.y, a1=(A1[j]-pr.x)*pr.y;
        float c0f=(B0[j]-pr.z)*pr.w, c1f=(B1[j]-pr.z)*pr.w;
        float n0 = fmaf(a0, wi0, fmaf(c0f, we0, bs0));
        float n1 = fmaf(a1, wi1, fmaf(c1f, we1, bs1));
        *(u32*)&SB[(pg*8+j)*136 + ch0] = packbf2(n0, n1);
      }
    } else {
      float si[8], sii[8], se[8], see[8];
      #pragma unroll
      for (int j=0;j<8;j++){
        float xi0=A0[j], xi1=A1[j], xe0=B0[j], xe1=B1[j];
        si[j]=xi0+xi1; sii[j]=fmaf(xi0,xi0,xi1*xi1);
        se[j]=xe0+xe1; see[j]=fmaf(xe0,xe0,xe1*xe1);
      }
      #pragma unroll
      for (int m=8;m<=32;m<<=1)
        #pragma unroll
        for (int j=0;j<8;j++){
          si[j]+=__shfl_xor(si[j],m); sii[j]+=__shfl_xor(sii[j],m);
          se[j]+=__shfl_xor(se[j],m); see[j]+=__shfl_xor(see[j],m);
        }
      if ((chg&7)==0){
        #pragma unroll
        for (int j=0;j<8;j++){
          spart[wave][pg*8+j][0]=si[j]; spart[wave][pg*8+j][1]=sii[j];
          spart[wave][pg*8+j][2]=se[j]; spart[wave][pg*8+j][3]=see[j];
        }
      }
      __syncthreads();
      if (t<64){
        float S0=0,S1=0,S2=0,S3=0;
        #pragma unroll
        for (int w=0;w<4;w++){ S0+=spart[w][t][0]; S1+=spart[w][t][1]; S2+=spart[w][t][2]; S3+=spart[w][t][3]; }
        const float inv=0.015625f;
        float mu_i=S0*inv, mu_e=S2*inv;
        float r_i=rsqrtf(fmaf(S1,inv,-mu_i*mu_i)+1e-5f);
        float r_e=rsqrtf(fmaf(S3,inv,-mu_e*mu_e)+1e-5f);
        params[t][0]=mu_i; params[t][1]=r_i; params[t][2]=mu_e; params[t][3]=r_e;
      }
      __syncthreads();
      #pragma unroll
      for (int j=0;j<8;j++){
        float4 pr = *(const float4*)&params[pg*8+j][0];
        float a0=(A0[j]-pr.x)*pr.y, a1=(A1[j]-pr.x)*pr.y;
        float c0f=(B0[j]-pr.z)*pr.w, c1f=(B1[j]-pr.z)*pr.w;
        float n0 = fmaf(a0, wi0, fmaf(c0f, we0, bs0));
        float n1 = fmaf(a1, wi1, fmaf(c1f, we1, bs1));
        *(u32*)&SB[(pg*8+j)*136 + ch0] = packbf2(n0, n1);
      }
    }
    __syncthreads();
    // GEMM1 (wave-local rows from here on)
    float4v acc1[4];
    #pragma unroll
    for (int nj=0;nj<4;nj++) acc1[nj]=(float4v)0.f;
    const int px_row = wave*16 + l15;
    #pragma unroll
    for (int ks=0;ks<2;ks++){
      const int off = ks*32 + quad*8;
      short8 af = *(const short8*)&SB[px_row*136 + off];
      #pragma unroll
      for (int nj=0;nj<4;nj++){
        short8 bw = *(const short8*)&PcL[(nj*16+l15)*72 + off];
        acc1[nj] = __builtin_amdgcn_mfma_f32_16x16x32_bf16(af, bw, acc1[nj], 0,0,0);
      }
    }
    float s[4], sq[4];
    #pragma unroll
    for (int j=0;j<4;j++){
      s[j] = acc1[0][j]+acc1[1][j]+acc1[2][j]+acc1[3][j];
      sq[j] = acc1[0][j]*acc1[0][j];
      sq[j] = fmaf(acc1[1][j],acc1[1][j],sq[j]);
      sq[j] = fmaf(acc1[2][j],acc1[2][j],sq[j]);
      sq[j] = fmaf(acc1[3][j],acc1[3][j],sq[j]);
    }
    #pragma unroll
    for (int m=1;m<=8;m<<=1)
      #pragma unroll
      for (int j=0;j<4;j++){ s[j]+=__shfl_xor(s[j],m); sq[j]+=__shfl_xor(sq[j],m); }
    float muj[4], rj[4];
    #pragma unroll
    for (int j=0;j<4;j++){
      muj[j]=s[j]*0.015625f;
      rj[j]=rsqrtf(fmaf(sq[j],0.015625f,-muj[j]*muj[j])+1e-5f);
    }
    #pragma unroll
    for (int nj=0;nj<4;nj++)
      #pragma unroll
      for (int j=0;j<4;j++){
        float tv = (acc1[nj][j]-muj[j])*rj[j];
        tv = fmaf(tv, w1r[nj], b1r[nj]);
        SB[(wave*16+quad*4+j)*136 + nj*16+l15] = f2bf(tv);
      }
    float4v accF[8];
    #pragma unroll
    for (int nh=0;nh<8;nh++) accF[nh]=(float4v)0.f;
    #pragma unroll
    for (int ks=0;ks<2;ks++){
      const int off = ks*32+quad*8;
      short8 af = *(const short8*)&SB[px_row*136 + off];
      #pragma unroll
      for (int nh=0;nh<8;nh++){
        short8 bw = *(const short8*)&fc1L[(nh*16+l15)*72 + off];
        accF[nh] = __builtin_amdgcn_mfma_f32_16x16x32_bf16(af, bw, accF[nh], 0,0,0);
      }
    }
    #pragma unroll
    for (int nh=0;nh<8;nh++){
      float bb = b1L[nh*16+l15];
      #pragma unroll
      for (int j=0;j<4;j++){
        float v = accF[nh][j] + bb;
        float g = 0.5f*v*(1.0f + erff(v*0.70710678118654752f));
        SB[(wave*16+quad*4+j)*136 + nh*16+l15] = f2bf(g);
      }
    }
    float4v accO[4];
    #pragma unroll
    for (int nj=0;nj<4;nj++) accO[nj]=(float4v)0.f;
    #pragma unroll
    for (int ks=0;ks<4;ks++){
      const int off = ks*32+quad*8;
      short8 ag = *(const short8*)&SB[px_row*136 + off];
      #pragma unroll
      for (int nj=0;nj<4;nj++){
        short8 bw = *(const short8*)&fc2L[(nj*16+l15)*136 + off];
        accO[nj] = __builtin_amdgcn_mfma_f32_16x16x32_bf16(ag, bw, accO[nj], 0,0,0);
      }
    }
    const int px0 = p0 + wave*16 + quad*4;
    #pragma unroll
    for (int nj=0;nj<4;nj++){
      float bb = b2L[nj*16+l15];
      int r = nj*16+l15;
      float v0 = acc1[nj][0] + accO[nj][0] + bb;
      float v1 = acc1[nj][1] + accO[nj][1] + bb;
      float v2 = acc1[nj][2] + accO[nj][2] + bb;
      float v3 = acc1[nj][3] + accO[nj][3] + bb;
      size_t oi = obase + (size_t)(b*64 + r)*HW + px0;
      if (f32){ float4 fv; fv.x=v0; fv.y=v1; fv.z=v2; fv.w=v3;
        *(float4*)((float*)outp + oi) = fv; }
      else *(uint2*)((u16*)outp + oi) = make_uint2(packbf2(v0,v1), packbf2(v2,v3));
    }
    __syncthreads();   // protect SB rows from next iter's cross-wave n-hat write
  }
}

// ---------------------------------------------------------------------------
// K3 differential: od = P_id @ n_i + P_ed @ n_e, then LN/FFN/residual
// ---------------------------------------------------------------------------
__global__ __launch_bounds__(256) void k3_diff(
    const void* __restrict__ img, const void* __restrict__ evt,
    const u16* __restrict__ lniw, const u16* __restrict__ lnib,
    const u16* __restrict__ lnew, const u16* __restrict__ lneb,
    const u16* __restrict__ ln2w, const u16* __restrict__ ln2b,
    const u16* __restrict__ fc1w, const u16* __restrict__ fc1b,
    const u16* __restrict__ fc2w, const u16* __restrict__ fc2b,
    const float* __restrict__ Pmat, void* __restrict__ outp, size_t obase,
    const float* __restrict__ par, int use_par)
{
  __shared__ u16 fc1L[128*72];
  __shared__ u16 fc2L[64*136];
  __shared__ u16 PiL[64*72];
  __shared__ u16 PeL[64*72];
  __shared__ u16 N2L[64*144];
  __shared__ float spart[4][64][4];
  __shared__ float params[64][4];
  __shared__ float b1L[128];
  __shared__ float b2L[64];
  __shared__ int s_cnt;

  const int t = threadIdx.x;
  const bool f32 = detect_f32(img, t, &s_cnt);
  const u16* imgb = (const u16*)img; const float* imgf = (const float*)img;
  const u16* evtb = (const u16*)evt; const float* evtf = (const float*)evt;

  const int b = blockIdx.x >> 8;
  const int P0 = (blockIdx.x & 255) * 256;
  const int chg = t >> 3, pg = t & 7, ch0 = chg*2;
  const int wave = t >> 6, lane = t & 63, l15 = lane & 15, quad = lane >> 4;

  { int row = t >> 1, c0 = (t & 1)*32;
    const uint4* s = (const uint4*)(fc1w + row*64 + c0);
    uint4* d = (uint4*)&fc1L[row*72 + c0];
    d[0]=s[0]; d[1]=s[1]; d[2]=s[2]; d[3]=s[3]; }
  { int row = t >> 2, c0 = (t & 3)*32;
    const uint4* s = (const uint4*)(fc2w + row*128 + c0);
    uint4* d = (uint4*)&fc2L[row*136 + c0];
    d[0]=s[0]; d[1]=s[1]; d[2]=s[2]; d[3]=s[3]; }
  { int row = t >> 2, c0 = (t & 3)*16;
    const float* si_ = Pmat + ((size_t)1*NBATCH + b)*4096 + row*64 + c0;
    const float* se_ = Pmat + ((size_t)2*NBATCH + b)*4096 + row*64 + c0;
    u32 u[8];
    #pragma unroll
    for (int i=0;i<8;i++) u[i] = packbf2(si_[2*i], si_[2*i+1]);
    uint4* d = (uint4*)&PiL[row*72 + c0];
    d[0] = make_uint4(u[0],u[1],u[2],u[3]); d[1] = make_uint4(u[4],u[5],u[6],u[7]);
    #pragma unroll
    for (int i=0;i<8;i++) u[i] = packbf2(se_[2*i], se_[2*i+1]);
    uint4* d2 = (uint4*)&PeL[row*72 + c0];
    d2[0] = make_uint4(u[0],u[1],u[2],u[3]); d2[1] = make_uint4(u[4],u[5],u[6],u[7]); }
  if (t < 128) b1L[t] = bf2f(fc1b[t]);
  if (t < 64)  b2L[t] = bf2f(fc2b[t]);

  float wi0=bf2f(lniw[ch0]), wi1=bf2f(lniw[ch0+1]);
  float bi0=bf2f(lnib[ch0]), bi1=bf2f(lnib[ch0+1]);
  float we0=bf2f(lnew[ch0]), we1=bf2f(lnew[ch0+1]);
  float be0=bf2f(lneb[ch0]), be1=bf2f(lneb[ch0+1]);
  float w1r[4], b1r[4];
  #pragma unroll
  for (int nj=0;nj<4;nj++){ w1r[nj]=bf2f(ln2w[nj*16+l15]); b1r[nj]=bf2f(ln2b[nj*16+l15]); }
  __syncthreads();

  const size_t base_i = (size_t)(b*64 + ch0)*HW;
  for (int it=0; it<4; ++it){
    const int p0 = P0 + it*64;
    float A0[8], A1[8], B0[8], B1[8];
    ld8(imgb, imgf, base_i + p0 + pg*8, f32, A0);
    ld8(imgb, imgf, base_i + HW + p0 + pg*8, f32, A1);
    ld8(evtb, evtf, base_i + p0 + pg*8, f32, B0);
    ld8(evtb, evtf, base_i + HW + p0 + pg*8, f32, B1);

    if (use_par){
      const float4* pp = (const float4*)(par + ((size_t)b*HW + p0 + pg*8)*4);
      #pragma unroll
      for (int j=0;j<8;j++){
        float4 pr = pp[j];
        float a0=(A0[j]-pr.x)*pr.y, a1=(A1[j]-pr.x)*pr.y;
        float c0f=(B0[j]-pr.z)*pr.w, c1f=(B1[j]-pr.z)*pr.w;
        *(u32*)&N2L[(pg*8+j)*144 + ch0]      = packbf2(fmaf(a0,wi0,bi0), fmaf(a1,wi1,bi1));
        *(u32*)&N2L[(pg*8+j)*144 + 72 + ch0] = packbf2(fmaf(c0f,we0,be0), fmaf(c1f,we1,be1));
      }
    } else {
      float si[8], sii[8], se[8], see[8];
      #pragma unroll
      for (int j=0;j<8;j++){
        float xi0=A0[j], xi1=A1[j], xe0=B0[j], xe1=B1[j];
        si[j]=xi0+xi1; sii[j]=fmaf(xi0,xi0,xi1*xi1);
        se[j]=xe0+xe1; see[j]=fmaf(xe0,xe0,xe1*xe1);
      }
      #pragma unroll
      for (int m=8;m<=32;m<<=1)
        #pragma unroll
        for (int j=0;j<8;j++){
          si[j]+=__shfl_xor(si[j],m); sii[j]+=__shfl_xor(sii[j],m);
          se[j]+=__shfl_xor(se[j],m); see[j]+=__shfl_xor(see[j],m);
        }
      if ((chg&7)==0){
        #pragma unroll
        for (int j=0;j<8;j++){
          spart[wave][pg*8+j][0]=si[j]; spart[wave][pg*8+j][1]=sii[j];
          spart[wave][pg*8+j][2]=se[j]; spart[wave][pg*8+j][3]=see[j];
        }
      }
      __syncthreads();
      if (t<64){
        float S0=0,S1=0,S2=0,S3=0;
        #pragma unroll
        for (int w=0;w<4;w++){ S0+=spart[w][t][0]; S1+=spart[w][t][1]; S2+=spart[w][t][2]; S3+=spart[w][t][3]; }
        const float inv=0.015625f;
        float mu_i=S0*inv, mu_e=S2*inv;
        float r_i=rsqrtf(fmaf(S1,inv,-mu_i*mu_i)+1e-5f);
        float r_e=rsqrtf(fmaf(S3,inv,-mu_e*mu_e)+1e-5f);
        params[t][0]=mu_i; params[t][1]=r_i; params[t][2]=mu_e; params[t][3]=r_e;
      }
      __syncthreads();
      #pragma unroll
      for (int j=0;j<8;j++){
        float4 pr = *(const float4*)&params[pg*8+j][0];
        float a0=(A0[j]-pr.x)*pr.y, a1=(A1[j]-pr.x)*pr.y;
        float c0f=(B0[j]-pr.z)*pr.w, c1f=(B1[j]-pr.z)*pr.w;
        *(u32*)&N2L[(pg*8+j)*144 + ch0]      = packbf2(fmaf(a0,wi0,bi0), fmaf(a1,wi1,bi1));
        *(u32*)&N2L[(pg*8+j)*144 + 72 + ch0] = packbf2(fmaf(c0f,we0,be0), fmaf(c1f,we1,be1));
      }
    }
    __syncthreads();
    float4v acc1[4];
    #pragma unroll
    for (int nj=0;nj<4;nj++) acc1[nj]=(float4v)0.f;
    const int px_row = wave*16 + l15;
    #pragma unroll
    for (int ks=0;ks<2;ks++){
      const int off = ks*32 + quad*8;
      short8 ai = *(const short8*)&N2L[px_row*144 + off];
      short8 ae = *(const short8*)&N2L[px_row*144 + 72 + off];
      #pragma unroll
      for (int nj=0;nj<4;nj++){
        short8 bwi = *(const short8*)&PiL[(nj*16+l15)*72 + off];
        acc1[nj] = __builtin_amdgcn_mfma_f32_16x16x32_bf16(ai, bwi, acc1[nj], 0,0,0);
        short8 bwe = *(const short8*)&PeL[(nj*16+l15)*72 + off];
        acc1[nj] = __builtin_amdgcn_mfma_f32_16x16x32_bf16(ae, bwe, acc1[nj], 0,0,0);
      }
    }
    float s[4], sq[4];
    #pragma unroll
    for (int j=0;j<4;j++){
      s[j] = acc1[0][j]+acc1[1][j]+acc1[2][j]+acc1[3][j];
      sq[j] = acc1[0][j]*acc1[0][j];
      sq[j] = fmaf(acc1[1][j],acc1[1][j],sq[j]);
      sq[j] = fmaf(acc1[2][j],acc1[2][j],sq[j]);
      sq[j] = fmaf(acc1[3][j],acc1[3][j],sq[j]);
    }
    #pragma unroll
    for (int m=1;m<=8;m<<=1)
      #pragma unroll
      for (int j=0;j<4;j++){ s[j]+=__shfl_xor(s[j],m); sq[j]+=__shfl_xor(sq[j],m); }
    float muj[4], rj[4];
    #pragma unroll
    for (int j=0;j<4;j++){
      muj[j]=s[j]*0.015625f;
      rj[j]=rsqrtf(fmaf(sq[j],0.015625f,-muj[j]*muj[j])+1e-5f);
    }
    #pragma unroll
    for (int nj=0;nj<4;nj++)
      #pragma unroll
      for (int j=0;j<4;j++){
        float tv = (acc1[nj][j]-muj[j])*rj[j];
        tv = fmaf(tv, w1r[nj], b1r[nj]);
        N2L[(wave*16+quad*4+j)*144 + nj*16+l15] = f2bf(tv);
      }
    float4v accF[8];
    #pragma unroll
    for (int nh=0;nh<8;nh++) accF[nh]=(float4v)0.f;
    #pragma unroll
    for (int ks=0;ks<2;ks++){
      const int off = ks*32+quad*8;
      short8 af = *(const short8*)&N2L[px_row*144 + off];
      #pragma unroll
      for (int nh=0;nh<8;nh++){
        short8 bw = *(const short8*)&fc1L[(nh*16+l15)*72 + off];
        accF[nh] = __builtin_amdgcn_mfma_f32_16x16x32_bf16(af, bw, accF[nh], 0,0,0);
      }
    }
    #pragma unroll
    for (int nh=0;nh<8;nh++){
      float bb = b1L[nh*16+l15];
      #pragma unroll
      for (int j=0;j<4;j++){
        float v = accF[nh][j] + bb;
        float g = 0.5f*v*(1.0f + erff(v*0.70710678118654752f));
        N2L[(wave*16+quad*4+j)*144 + nh*16+l15] = f2bf(g);
      }
    }
    float4v accO[4];
    #pragma unroll
    for (int nj=0;nj<4;nj++) accO[nj]=(float4v)0.f;
    #pragma unroll
    for (int ks=0;ks<4;ks++){
      const int off = ks*32+quad*8;
      short8 ag = *(const short8*)&N2L[px_row*144 + off];
      #pragma unroll
      for (int nj=0;nj<4;nj++){
        short8 bw = *(const short8*)&fc2L[(nj*16+l15)*136 + off];
        accO[nj] = __builtin_amdgcn_mfma_f32_16x16x32_bf16(ag, bw, accO[nj], 0,0,0);
      }
    }
    const int px0 = p0 + wave*16 + quad*4;
    #pragma unroll
    for (int nj=0;nj<4;nj++){
      float bb = b2L[nj*16+l15];
      int r = nj*16+l15;
      float v0 = acc1[nj][0] + accO[nj][0] + bb;
      float v1 = acc1[nj][1] + accO[nj][1] + bb;
      float v2 = acc1[nj][2] + accO[nj][2] + bb;
      float v3 = acc1[nj][3] + accO[nj][3] + bb;
      size_t oi = obase + (size_t)(b*64 + r)*HW + px0;
      if (f32){ float4 fv; fv.x=v0; fv.y=v1; fv.z=v2; fv.w=v3;
        *(float4*)((float*)outp + oi) = fv; }
      else *(uint2*)((u16*)outp + oi) = make_uint2(packbf2(v0,v1), packbf2(v2,v3));
    }
    __syncthreads();
  }
}

extern "C" void kernel_launch(void* const* d_in, const int* in_sizes, int n_in,
                              void* d_out, int out_size, void* d_ws, size_t ws_size,
                              hipStream_t stream)
{
  const void* img = d_in[0];
  const void* evt = d_in[1];
  float* ws = (float*)d_ws;
  u16* wc = (u16*)(ws + OFF_WC);
  float* par = ws + OFF_PAR;
  const int use_par = (ws_size >= WS_NEED) ? 1 : 0;
  #define SLOT(i) (wc + (size_t)((i)-2)*8192)

  hipMemsetAsync(ws, 0, 131072*sizeof(float), stream);
  convert_all<<<dim3(30), dim3(256), 0, stream>>>(img,
      d_in[2], d_in[3], d_in[4], d_in[5], d_in[6], d_in[7], d_in[8], d_in[9],
      d_in[10], d_in[11], d_in[12], d_in[13], d_in[14], d_in[15], d_in[16], d_in[17],
      d_in[18], d_in[19], d_in[20], d_in[21], d_in[22], d_in[23], d_in[24], d_in[25],
      d_in[26], d_in[27], d_in[28], d_in[29], d_in[30], d_in[31], wc);
  k1_cov<<<dim3(512), dim3(256), 0, stream>>>(img, evt,
      SLOT(10), SLOT(11), SLOT(12), SLOT(13), SLOT(14), SLOT(15), SLOT(16), SLOT(17),
      ws, par, use_par);
  p2a<<<dim3(40), dim3(256), 0, stream>>>(SLOT(2), SLOT(3), SLOT(6), SLOT(7), ws);
  p2b<<<dim3(4), dim3(256), 0, stream>>>(ws, SLOT(2), SLOT(3), SLOT(6), SLOT(7),
      SLOT(4), SLOT(8), SLOT(5), SLOT(9));
  p2c<<<dim3(12), dim3(256), 0, stream>>>(SLOT(30), SLOT(31), ws);
  k3_common<<<dim3(1024), dim3(256), 0, stream>>>(img, evt,
      SLOT(10), SLOT(11), SLOT(12), SLOT(13), SLOT(18), SLOT(19),
      SLOT(22), SLOT(23), SLOT(24), SLOT(25), ws + OFF_P, d_out, (size_t)0, par, use_par);
  k3_diff<<<dim3(1024), dim3(256), 0, stream>>>(img, evt,
      SLOT(10), SLOT(11), SLOT(12), SLOT(13), SLOT(20), SLOT(21),
      SLOT(26), SLOT(27), SLOT(28), SLOT(29), ws + OFF_P, d_out, (size_t)16777216, par, use_par);
  #undef SLOT
}